// Round 1
// baseline (235.008 us; speedup 1.0000x reference)
//
#include <hip/hip_runtime.h>
#include <hip/hip_bf16.h>
#include <math.h>

#define CHN 512
#define NHEADS 8
#define DHEAD 32
#define HW 4096
#define LN_EPS 1e-5f

typedef short short8 __attribute__((ext_vector_type(8)));
typedef float float4v __attribute__((ext_vector_type(4)));

__device__ __forceinline__ unsigned short f2bf(float f) {
    unsigned int u = __float_as_uint(f);
    u = (u + 0x7FFFu + ((u >> 16) & 1u)) >> 16;
    return (unsigned short)u;
}

// ---------------- kernel 1: weight fp32 -> bf16 ----------------
__global__ void k_convert(const float* __restrict__ wq, const float* __restrict__ wp,
                          unsigned short* __restrict__ wqbf, unsigned short* __restrict__ wpbf) {
    int i = blockIdx.x * 256 + threadIdx.x;
    if (i < 768 * 512) wqbf[i] = f2bf(wq[i]);
    if (i < 512 * 256) wpbf[i] = f2bf(wp[i]);
}

// ---------------- kernel 2: pos bias bilinear 16 -> 64 ----------------
__global__ void k_pos(const float* __restrict__ pb, float* __restrict__ pos) {
    int i = blockIdx.x * 256 + threadIdx.x;
    if (i >= NHEADS * HW) return;
    int h = i >> 12, p = i & 4095, y = p >> 6, x = p & 63;
    float sy = y * 0.25f - 0.375f, sx = x * 0.25f - 0.375f;
    float fy = floorf(sy), fx = floorf(sx);
    float wy = sy - fy, wx = sx - fx;
    int y0 = (int)fy, x0 = (int)fx;
    int y1 = y0 + 1 < 15 ? y0 + 1 : 15;
    int x1 = x0 + 1 < 15 ? x0 + 1 : 15;
    y0 = y0 > 0 ? y0 : 0;
    x0 = x0 > 0 ? x0 : 0;
    const float* src = pb + h * 256;
    float v = (1.f - wy) * ((1.f - wx) * src[y0 * 16 + x0] + wx * src[y0 * 16 + x1]) +
              wy * ((1.f - wx) * src[y1 * 16 + x0] + wx * src[y1 * 16 + x1]);
    pos[i] = v;
}

// ---------------- kernel 3: QKV GEMM  qkv[768][4096] = w_qkv[768][512] * x[512][4096] ----------------
__global__ __launch_bounds__(256) void k_qkv(const unsigned short* __restrict__ wbf,
                                             const float* __restrict__ x,
                                             float* __restrict__ qkv) {
    __shared__ __attribute__((aligned(16))) unsigned short xs[64][72]; // [p][c], padded
    int m0 = (blockIdx.x >> 6) * 64;
    int p0 = (blockIdx.x & 63) * 64;
    int t = threadIdx.x;
    int wave = t >> 6, lane = t & 63, quad = lane >> 4, l16 = lane & 15;
    int sp = t & 63;            // staging p
    int scb = (t >> 6) * 16;    // staging c base

    float4v acc[4] = {};
    for (int k0 = 0; k0 < 512; k0 += 64) {
        __syncthreads();
        short8 v0, v1;
        #pragma unroll
        for (int cc = 0; cc < 8; cc++)
            v0[cc] = (short)f2bf(x[(k0 + scb + cc) * HW + p0 + sp]);
        #pragma unroll
        for (int cc = 0; cc < 8; cc++)
            v1[cc] = (short)f2bf(x[(k0 + scb + 8 + cc) * HW + p0 + sp]);
        *(short8*)&xs[sp][scb] = v0;
        *(short8*)&xs[sp][scb + 8] = v1;
        __syncthreads();
        #pragma unroll
        for (int kc = 0; kc < 2; kc++) {
            short8 a = *(const short8*)&wbf[(m0 + wave * 16 + l16) * 512 + k0 + kc * 32 + quad * 8];
            #pragma unroll
            for (int nt = 0; nt < 4; nt++) {
                short8 b = *(const short8*)&xs[nt * 16 + l16][kc * 32 + quad * 8];
                acc[nt] = __builtin_amdgcn_mfma_f32_16x16x32_bf16(a, b, acc[nt], 0, 0, 0);
            }
        }
    }
    #pragma unroll
    for (int nt = 0; nt < 4; nt++)
        #pragma unroll
        for (int r = 0; r < 4; r++)
            qkv[(m0 + wave * 16 + quad * 4 + r) * HW + p0 + nt * 16 + l16] = acc[nt][r];
}

// ---------------- kernel 4: flash attention per (head, 64-query block) ----------------
__global__ __launch_bounds__(256) void k_attn(const float* __restrict__ qkv,
                                              const float* __restrict__ pos,
                                              float* __restrict__ yT) {
    __shared__ __attribute__((aligned(16))) unsigned short ks[64][40];     // [j][d]
    __shared__ __attribute__((aligned(16))) unsigned short vs[32][72];     // [d][j]
    __shared__ __attribute__((aligned(16))) unsigned short ps[4][16][72];  // per-wave P [m][j]
    int h = blockIdx.x >> 6;
    int i0 = (blockIdx.x & 63) * 64;
    int t = threadIdx.x, wave = t >> 6, lane = t & 63, quad = lane >> 4, l16 = lane & 15;
    const float scale = 0.17677669529663687f; // 1/sqrt(32)

    // Q fragment (A-layout): m=l16 -> query, k=quad*8+idx -> d
    short8 qf;
    {
        int i = i0 + wave * 16 + l16;
        #pragma unroll
        for (int idx = 0; idx < 8; idx++) {
            int d = quad * 8 + idx;
            qf[idx] = (short)f2bf(qkv[(h * 32 + d) * HW + i] * scale);
        }
    }
    float m_i[4], l_i[4];
    float4v o0 = {}, o1 = {};
    #pragma unroll
    for (int r = 0; r < 4; r++) { m_i[r] = -1e30f; l_i[r] = 0.f; }

    int sj = t & 63, sdb = (t >> 6) * 8;   // K staging
    int vd = t >> 3, vjb = (t & 7) * 8;    // V staging

    for (int j0 = 0; j0 < HW; j0 += 64) {
        __syncthreads();
        {   // K tile -> [j][d]
            short8 v;
            #pragma unroll
            for (int dd = 0; dd < 8; dd++)
                v[dd] = (short)f2bf(qkv[(256 + h * 32 + sdb + dd) * HW + j0 + sj]);
            *(short8*)&ks[sj][sdb] = v;
        }
        {   // V tile -> [d][j]
            short8 v;
            #pragma unroll
            for (int jj = 0; jj < 8; jj++)
                v[jj] = (short)f2bf(qkv[(512 + h * 32 + vd) * HW + j0 + vjb + jj]);
            *(short8*)&vs[vd][vjb] = v;
        }
        __syncthreads();

        // S = scale*Q.K^T + pos[j]   (4 sub-tiles of 16 j each)
        float s[4][4];
        #pragma unroll
        for (int st = 0; st < 4; st++) {
            short8 kb = *(const short8*)&ks[st * 16 + l16][quad * 8];
            float4v d = __builtin_amdgcn_mfma_f32_16x16x32_bf16(qf, kb, (float4v){0.f, 0.f, 0.f, 0.f}, 0, 0, 0);
            float pj = pos[h * HW + j0 + st * 16 + l16];
            #pragma unroll
            for (int r = 0; r < 4; r++) s[st][r] = d[r] + pj;
        }
        // online softmax (rows = quad*4+r, spread over 16 lanes of the quad)
        float mnew[4], alpha[4];
        #pragma unroll
        for (int r = 0; r < 4; r++) {
            float mx = fmaxf(fmaxf(s[0][r], s[1][r]), fmaxf(s[2][r], s[3][r]));
            #pragma unroll
            for (int off = 1; off < 16; off <<= 1)
                mx = fmaxf(mx, __shfl_xor(mx, off, 64));
            mnew[r] = fmaxf(m_i[r], mx);
            alpha[r] = __expf(m_i[r] - mnew[r]);
            m_i[r] = mnew[r];
        }
        #pragma unroll
        for (int st = 0; st < 4; st++)
            #pragma unroll
            for (int r = 0; r < 4; r++)
                s[st][r] = __expf(s[st][r] - mnew[r]);
        #pragma unroll
        for (int r = 0; r < 4; r++) {
            float rs = s[0][r] + s[1][r] + s[2][r] + s[3][r];
            #pragma unroll
            for (int off = 1; off < 16; off <<= 1)
                rs += __shfl_xor(rs, off, 64);
            l_i[r] = l_i[r] * alpha[r] + rs;
        }
        // P -> LDS (C/D layout write), reread in A layout
        #pragma unroll
        for (int st = 0; st < 4; st++)
            #pragma unroll
            for (int r = 0; r < 4; r++)
                ps[wave][quad * 4 + r][st * 16 + l16] = f2bf(s[st][r]);
        #pragma unroll
        for (int r = 0; r < 4; r++) { o0[r] *= alpha[r]; o1[r] *= alpha[r]; }
        __syncthreads();
        #pragma unroll
        for (int c = 0; c < 2; c++) {
            short8 pa = *(const short8*)&ps[wave][l16][c * 32 + quad * 8];
            short8 vb0 = *(const short8*)&vs[l16][c * 32 + quad * 8];
            short8 vb1 = *(const short8*)&vs[16 + l16][c * 32 + quad * 8];
            o0 = __builtin_amdgcn_mfma_f32_16x16x32_bf16(pa, vb0, o0, 0, 0, 0);
            o1 = __builtin_amdgcn_mfma_f32_16x16x32_bf16(pa, vb1, o1, 0, 0, 0);
        }
    }
    #pragma unroll
    for (int r = 0; r < 4; r++) {
        float inv = 1.f / l_i[r];
        int i = i0 + wave * 16 + quad * 4 + r;
        yT[i * 256 + h * 32 + l16] = o0[r] * inv;
        yT[i * 256 + h * 32 + 16 + l16] = o1[r] * inv;
    }
}

// ---------------- kernel 5: proj GEMM + bias + residual + LayerNorm ----------------
__global__ __launch_bounds__(256) void k_proj_ln(const unsigned short* __restrict__ wpbf,
                                                 const float* __restrict__ yT,
                                                 const float* __restrict__ x,
                                                 const float* __restrict__ b_proj,
                                                 const float* __restrict__ gamma,
                                                 const float* __restrict__ beta,
                                                 float* __restrict__ out) {
    __shared__ __attribute__((aligned(16))) unsigned short ys[16][264]; // [p][o] padded
    __shared__ float red[2][4][16];
    int p0 = blockIdx.x * 16;
    int t = threadIdx.x, wave = t >> 6, lane = t & 63, quad = lane >> 4, l16 = lane & 15;
    {
        int p = t >> 4, ob = (t & 15) * 16;
        short8 v0, v1;
        #pragma unroll
        for (int i = 0; i < 8; i++) v0[i] = (short)f2bf(yT[(p0 + p) * 256 + ob + i]);
        #pragma unroll
        for (int i = 0; i < 8; i++) v1[i] = (short)f2bf(yT[(p0 + p) * 256 + ob + 8 + i]);
        *(short8*)&ys[p][ob] = v0;
        *(short8*)&ys[p][ob + 8] = v1;
    }
    __syncthreads();
    float4v acc[8] = {};
    #pragma unroll
    for (int kc = 0; kc < 8; kc++) {
        short8 b = *(const short8*)&ys[l16][kc * 32 + quad * 8];
        #pragma unroll
        for (int mt = 0; mt < 8; mt++) {
            short8 a = *(const short8*)&wpbf[(wave * 128 + mt * 16 + l16) * 256 + kc * 32 + quad * 8];
            acc[mt] = __builtin_amdgcn_mfma_f32_16x16x32_bf16(a, b, acc[mt], 0, 0, 0);
        }
    }
    int p = p0 + l16;
    float sum = 0.f, sumsq = 0.f;
    #pragma unroll
    for (int mt = 0; mt < 8; mt++)
        #pragma unroll
        for (int r = 0; r < 4; r++) {
            int c = wave * 128 + mt * 16 + quad * 4 + r;
            float v = acc[mt][r] + b_proj[c] + x[c * HW + p];
            acc[mt][r] = v;
            sum += v;
            sumsq += v * v;
        }
    sum += __shfl_xor(sum, 16, 64);
    sum += __shfl_xor(sum, 32, 64);
    sumsq += __shfl_xor(sumsq, 16, 64);
    sumsq += __shfl_xor(sumsq, 32, 64);
    if (quad == 0) { red[0][wave][l16] = sum; red[1][wave][l16] = sumsq; }
    __syncthreads();
    float s0 = red[0][0][l16] + red[0][1][l16] + red[0][2][l16] + red[0][3][l16];
    float s1 = red[1][0][l16] + red[1][1][l16] + red[1][2][l16] + red[1][3][l16];
    float mean = s0 * (1.f / 512.f);
    float var = s1 * (1.f / 512.f) - mean * mean;
    float rstd = rsqrtf(var + LN_EPS);
    #pragma unroll
    for (int mt = 0; mt < 8; mt++)
        #pragma unroll
        for (int r = 0; r < 4; r++) {
            int c = wave * 128 + mt * 16 + quad * 4 + r;
            out[c * HW + p] = (acc[mt][r] - mean) * rstd * gamma[c] + beta[c];
        }
}

extern "C" void kernel_launch(void* const* d_in, const int* in_sizes, int n_in,
                              void* d_out, int out_size, void* d_ws, size_t ws_size,
                              hipStream_t stream) {
    const float* x       = (const float*)d_in[0];
    const float* w_qkv   = (const float*)d_in[1];
    const float* w_proj  = (const float*)d_in[2];
    const float* b_proj  = (const float*)d_in[3];
    const float* pos_b   = (const float*)d_in[4];
    const float* gamma   = (const float*)d_in[5];
    const float* beta    = (const float*)d_in[6];
    char* ws = (char*)d_ws;
    float* qkv          = (float*)ws;                          // 768*4096*4  = 12582912
    float* yT           = (float*)(ws + 12582912);             // 4096*256*4  = 4194304
    float* pos          = (float*)(ws + 16777216);             // 8*4096*4    = 131072
    unsigned short* wqbf = (unsigned short*)(ws + 16908288);   // 768*512*2   = 786432
    unsigned short* wpbf = (unsigned short*)(ws + 17694720);   // 512*256*2   = 262144

    k_convert<<<1536, 256, 0, stream>>>(w_qkv, w_proj, wqbf, wpbf);
    k_pos<<<128, 256, 0, stream>>>(pos_b, pos);
    k_qkv<<<768, 256, 0, stream>>>(wqbf, x, qkv);
    k_attn<<<512, 256, 0, stream>>>(qkv, pos, yT);
    k_proj_ln<<<256, 256, 0, stream>>>(wpbf, yT, x, b_proj, gamma, beta, (float*)d_out);
}

// Round 3
// 219.457 us; speedup vs baseline: 1.0709x; 1.0709x over previous
//
#include <hip/hip_runtime.h>
#include <hip/hip_bf16.h>
#include <math.h>

#define HW 4096
#define LN_EPS 1e-5f

typedef _Float16 half4v __attribute__((ext_vector_type(4)));
typedef _Float16 half8v __attribute__((ext_vector_type(8)));
typedef float float4v __attribute__((ext_vector_type(4)));

__device__ __forceinline__ half4v lo4(half8v v) { return __builtin_shufflevector(v, v, 0, 1, 2, 3); }
__device__ __forceinline__ half4v hi4(half8v v) { return __builtin_shufflevector(v, v, 4, 5, 6, 7); }

// perm32: stored position p holds index d = (p&3) + 4*((p>>3)&3) + 16*((p>>2)&1)
// so a b128 (8 halves) at p=quad*8 yields d = {quad*4+0..3, 16+quad*4+0..3} = the
// k-fragments of the two 16x16x16 MFMAs covering a 32-deep contraction.
__device__ __forceinline__ int inv32(int d) {
    return (d & 3) + (((d >> 4) & 1) << 2) + (((d >> 2) & 3) << 3);
}
// y swizzle: element (pos, o) stored at pos*256 + ((o>>3 ^ (pos&7))<<3) + (o&7)
__device__ __forceinline__ int yswz(int p, int o) {
    return ((((o >> 3) ^ (p & 7)) << 3) | (o & 7));
}

// ---------------- kernel 1: fp32 -> f16 conversions (x, w_qkv [Q-rows pre-scaled], w_proj) ----
__global__ void k_convert(const float* __restrict__ x, const float* __restrict__ wq,
                          const float* __restrict__ wp,
                          _Float16* __restrict__ xh, _Float16* __restrict__ wqh,
                          _Float16* __restrict__ wph) {
    const float qs = 0.17677669529663687f * 1.4426950408889634f; // scale * log2(e)
    int i = blockIdx.x * 256 + threadIdx.x;
    if (i < 512 * HW) xh[i] = (_Float16)x[i];
    if (i < 768 * 512) {
        float v = wq[i];
        wqh[i] = (_Float16)(i < 256 * 512 ? v * qs : v);
    }
    if (i < 512 * 256) wph[i] = (_Float16)wp[i];
}

// ---------------- kernel 2: pos bias bilinear 16 -> 64, times log2(e) ----------------
__global__ void k_pos(const float* __restrict__ pb, float* __restrict__ pos) {
    int i = blockIdx.x * 256 + threadIdx.x;
    if (i >= 8 * HW) return;
    int h = i >> 12, p = i & 4095, y = p >> 6, x = p & 63;
    float sy = y * 0.25f - 0.375f, sx = x * 0.25f - 0.375f;
    float fy = floorf(sy), fx = floorf(sx);
    float wy = sy - fy, wx = sx - fx;
    int y0 = (int)fy, x0 = (int)fx;
    int y1 = y0 + 1 < 15 ? y0 + 1 : 15;
    int x1 = x0 + 1 < 15 ? x0 + 1 : 15;
    y0 = y0 > 0 ? y0 : 0;
    x0 = x0 > 0 ? x0 : 0;
    const float* src = pb + h * 256;
    float v = (1.f - wy) * ((1.f - wx) * src[y0 * 16 + x0] + wx * src[y0 * 16 + x1]) +
              wy * ((1.f - wx) * src[y1 * 16 + x0] + wx * src[y1 * 16 + x1]);
    pos[i] = v * 1.4426950408889634f;
}

// ---------------- kernel 3: QKV GEMM (A = x^T staged in LDS, B = w from global) ----------
// Outputs permuted f16 layouts:
//   qa/ka: [h][pos][dperm32]  (Q pre-scaled by scale*log2e via wqh)
//   va:    [h*32+d][posperm32]
__global__ __launch_bounds__(256) void k_qkv(const _Float16* __restrict__ wqh,
                                             const _Float16* __restrict__ xh,
                                             _Float16* __restrict__ qa,
                                             _Float16* __restrict__ ka,
                                             _Float16* __restrict__ va) {
    __shared__ __attribute__((aligned(16))) _Float16 xs[64][72]; // [pos][c], padded
    int n0 = (blockIdx.x >> 6) * 64;  // out-channel tile base
    int p0 = (blockIdx.x & 63) * 64;  // position tile base
    int t = threadIdx.x, w = t >> 6, lane = t & 63, quad = lane >> 4, l16 = lane & 15;
    int sp = t & 63, scb = (t >> 6) * 16;

    float4v acc[4] = {};
    for (int k0 = 0; k0 < 512; k0 += 64) {
        __syncthreads();
        half8v v0, v1;
        #pragma unroll
        for (int cc = 0; cc < 8; cc++) v0[cc] = xh[(k0 + scb + cc) * HW + p0 + sp];
        #pragma unroll
        for (int cc = 0; cc < 8; cc++) v1[cc] = xh[(k0 + scb + 8 + cc) * HW + p0 + sp];
        *(half8v*)&xs[sp][scb] = v0;
        *(half8v*)&xs[sp][scb + 8] = v1;
        __syncthreads();
        #pragma unroll
        for (int kc = 0; kc < 2; kc++) {
            half8v a = *(const half8v*)&xs[w * 16 + l16][kc * 32 + quad * 8];
            #pragma unroll
            for (int nt = 0; nt < 4; nt++) {
                half8v b = *(const half8v*)&wqh[(n0 + nt * 16 + l16) * 512 + k0 + kc * 32 + quad * 8];
                acc[nt] = __builtin_amdgcn_mfma_f32_16x16x32_f16(a, b, acc[nt], 0, 0, 0);
            }
        }
    }
    // D: row=quad*4+r -> pos (this wave's 16-subtile), col=l16 -> out-channel
    #pragma unroll
    for (int nt = 0; nt < 4; nt++) {
        int o = n0 + nt * 16 + l16;
        #pragma unroll
        for (int r = 0; r < 4; r++) {
            int p = p0 + w * 16 + quad * 4 + r;
            _Float16 v = (_Float16)acc[nt][r];
            if (o < 256) {
                qa[(o >> 5) * 131072 + p * 32 + inv32(o & 31)] = v;
            } else if (o < 512) {
                ka[((o - 256) >> 5) * 131072 + p * 32 + inv32(o & 31)] = v;
            } else {
                va[(o - 512) * HW + (p & ~31) + inv32(p & 31)] = v;
            }
        }
    }
}

// ---------------- kernel 4: flash attention, LDS-free, no barriers, no online-max ----------
// S^T = K.Q^T via 16x16x16 MFMA: C-layout of S^T == A-layout of P for PV. No P roundtrip.
__global__ __launch_bounds__(256) void k_attn(const _Float16* __restrict__ qa,
                                              const _Float16* __restrict__ ka,
                                              const _Float16* __restrict__ va,
                                              const float* __restrict__ pos,
                                              _Float16* __restrict__ yh) {
    int h = blockIdx.x >> 6;
    int qb = (blockIdx.x & 63) * 64;
    int t = threadIdx.x, w = t >> 6, lane = t & 63, quad = lane >> 4, l16 = lane & 15;
    int q0 = qb + w * 16;

    half8v qf = *(const half8v*)(qa + h * 131072 + (q0 + l16) * 32 + quad * 8);
    half4v qlo = lo4(qf), qhi = hi4(qf);
    const _Float16* kptr = ka + h * 131072 + l16 * 32 + quad * 8;
    const _Float16* vptr0 = va + h * 131072 + l16 * HW + quad * 8;
    const _Float16* vptr1 = vptr0 + 16 * HW;
    const float* pp = pos + h * HW + quad * 4;

    float4v o0 = {}, o1 = {};
    float lsum = 0.f;
    const float4v zero = {0.f, 0.f, 0.f, 0.f};

    for (int j0 = 0; j0 < HW; j0 += 32) {
        half8v kf0 = *(const half8v*)(kptr + j0 * 32);        // rows j0+l16
        half8v kf1 = *(const half8v*)(kptr + j0 * 32 + 512);  // rows j0+16+l16
        half8v vf0 = *(const half8v*)(vptr0 + j0);            // d = l16
        half8v vf1 = *(const half8v*)(vptr1 + j0);            // d = 16+l16
        float4v pb0 = *(const float4v*)(pp + j0);
        float4v pb1 = *(const float4v*)(pp + j0 + 16);

        // S^T sub-tiles: rows j, col query. Already includes scale*log2e (in Q).
        float4v s0 = __builtin_amdgcn_mfma_f32_16x16x16f16(lo4(kf0), qlo, zero, 0, 0, 0);
        s0 = __builtin_amdgcn_mfma_f32_16x16x16f16(hi4(kf0), qhi, s0, 0, 0, 0);
        float4v s1 = __builtin_amdgcn_mfma_f32_16x16x16f16(lo4(kf1), qlo, zero, 0, 0, 0);
        s1 = __builtin_amdgcn_mfma_f32_16x16x16f16(hi4(kf1), qhi, s1, 0, 0, 0);

        float e0 = exp2f(s0[0] + pb0[0]);
        float e1 = exp2f(s0[1] + pb0[1]);
        float e2 = exp2f(s0[2] + pb0[2]);
        float e3 = exp2f(s0[3] + pb0[3]);
        float e4 = exp2f(s1[0] + pb1[0]);
        float e5 = exp2f(s1[1] + pb1[1]);
        float e6 = exp2f(s1[2] + pb1[2]);
        float e7 = exp2f(s1[3] + pb1[3]);
        lsum += ((e0 + e1) + (e2 + e3)) + ((e4 + e5) + (e6 + e7));

        half4v pa0, pa1;
        pa0[0] = (_Float16)e0; pa0[1] = (_Float16)e1;
        pa0[2] = (_Float16)e2; pa0[3] = (_Float16)e3;
        pa1[0] = (_Float16)e4; pa1[1] = (_Float16)e5;
        pa1[2] = (_Float16)e6; pa1[3] = (_Float16)e7;

        o0 = __builtin_amdgcn_mfma_f32_16x16x16f16(pa0, lo4(vf0), o0, 0, 0, 0);
        o0 = __builtin_amdgcn_mfma_f32_16x16x16f16(pa1, hi4(vf0), o0, 0, 0, 0);
        o1 = __builtin_amdgcn_mfma_f32_16x16x16f16(pa0, lo4(vf1), o1, 0, 0, 0);
        o1 = __builtin_amdgcn_mfma_f32_16x16x16f16(pa1, hi4(vf1), o1, 0, 0, 0);
    }
    // l: lane's partial is for query=l16; finish across quads once.
    lsum += __shfl_xor(lsum, 16, 64);
    lsum += __shfl_xor(lsum, 32, 64);
    // O D-layout: row=quad*4+r -> query, col=l16 -> d
    #pragma unroll
    for (int r = 0; r < 4; r++) {
        float lq = __shfl(lsum, quad * 4 + r, 64);
        float inv = 1.f / lq;
        int p = q0 + quad * 4 + r;
        int oc0 = h * 32 + l16, oc1 = oc0 + 16;
        yh[p * 256 + yswz(p, oc0)] = (_Float16)(o0[r] * inv);
        yh[p * 256 + yswz(p, oc1)] = (_Float16)(o1[r] * inv);
    }
}

// ---------------- kernel 5: proj GEMM + bias + residual + LayerNorm ----------------
__global__ __launch_bounds__(256) void k_proj_ln(const _Float16* __restrict__ wph,
                                                 const _Float16* __restrict__ yh,
                                                 const float* __restrict__ x,
                                                 const float* __restrict__ b_proj,
                                                 const float* __restrict__ gamma,
                                                 const float* __restrict__ beta,
                                                 float* __restrict__ out) {
    __shared__ __attribute__((aligned(16))) _Float16 ys[16 * 256]; // mirrors swizzled global
    __shared__ float red[2][4][16];
    int p0 = blockIdx.x * 16;
    int t = threadIdx.x, w = t >> 6, lane = t & 63, quad = lane >> 4, l16 = lane & 15;
    // linear b128 copy (global layout is pre-swizzled, so this stays conflict-free)
    *(half8v*)&ys[t * 8] = *(const half8v*)&yh[p0 * 256 + t * 8];
    *(half8v*)&ys[2048 + t * 8] = *(const half8v*)&yh[p0 * 256 + 2048 + t * 8];
    __syncthreads();
    float4v acc[8] = {};
    #pragma unroll
    for (int kc = 0; kc < 8; kc++) {
        int u = (kc * 4 + quad) ^ (l16 & 7);
        half8v b = *(const half8v*)&ys[l16 * 256 + u * 8];
        #pragma unroll
        for (int mt = 0; mt < 8; mt++) {
            half8v a = *(const half8v*)&wph[(w * 128 + mt * 16 + l16) * 256 + kc * 32 + quad * 8];
            acc[mt] = __builtin_amdgcn_mfma_f32_16x16x32_f16(a, b, acc[mt], 0, 0, 0);
        }
    }
    int p = p0 + l16;
    float sum = 0.f, sumsq = 0.f;
    #pragma unroll
    for (int mt = 0; mt < 8; mt++)
        #pragma unroll
        for (int r = 0; r < 4; r++) {
            int c = w * 128 + mt * 16 + quad * 4 + r;
            float v = acc[mt][r] + b_proj[c] + x[c * HW + p];
            acc[mt][r] = v;
            sum += v;
            sumsq += v * v;
        }
    sum += __shfl_xor(sum, 16, 64);
    sum += __shfl_xor(sum, 32, 64);
    sumsq += __shfl_xor(sumsq, 16, 64);
    sumsq += __shfl_xor(sumsq, 32, 64);
    if (quad == 0) { red[0][w][l16] = sum; red[1][w][l16] = sumsq; }
    __syncthreads();
    float s0 = red[0][0][l16] + red[0][1][l16] + red[0][2][l16] + red[0][3][l16];
    float s1 = red[1][0][l16] + red[1][1][l16] + red[1][2][l16] + red[1][3][l16];
    float mean = s0 * (1.f / 512.f);
    float var = s1 * (1.f / 512.f) - mean * mean;
    float rstd = rsqrtf(var + LN_EPS);
    #pragma unroll
    for (int mt = 0; mt < 8; mt++)
        #pragma unroll
        for (int r = 0; r < 4; r++) {
            int c = w * 128 + mt * 16 + quad * 4 + r;
            out[c * HW + p] = (acc[mt][r] - mean) * rstd * gamma[c] + beta[c];
        }
}

extern "C" void kernel_launch(void* const* d_in, const int* in_sizes, int n_in,
                              void* d_out, int out_size, void* d_ws, size_t ws_size,
                              hipStream_t stream) {
    const float* x      = (const float*)d_in[0];
    const float* w_qkv  = (const float*)d_in[1];
    const float* w_proj = (const float*)d_in[2];
    const float* b_proj = (const float*)d_in[3];
    const float* pos_b  = (const float*)d_in[4];
    const float* gamma  = (const float*)d_in[5];
    const float* beta   = (const float*)d_in[6];
    char* ws = (char*)d_ws;
    _Float16* xh  = (_Float16*)(ws);              // 512*4096*2   = 4194304
    _Float16* qa  = (_Float16*)(ws + 4194304);    // 8*4096*32*2  = 2097152
    _Float16* ka  = (_Float16*)(ws + 6291456);    // 2097152
    _Float16* va  = (_Float16*)(ws + 8388608);    // 2097152
    _Float16* yh  = (_Float16*)(ws + 10485760);   // 4096*256*2   = 2097152
    float*    pos = (float*)   (ws + 12582912);   // 8*4096*4     = 131072
    _Float16* wqh = (_Float16*)(ws + 12714240);   // 768*512*2    = 786432 (16B-aligned base)
    _Float16* wph = (_Float16*)(ws + 13500672);   // 512*256*2    = 262144

    k_convert<<<8192, 256, 0, stream>>>(x, w_qkv, w_proj, xh, wqh, wph);
    k_pos<<<128, 256, 0, stream>>>(pos_b, pos);
    k_qkv<<<768, 256, 0, stream>>>(wqh, xh, qa, ka, va);
    k_attn<<<512, 256, 0, stream>>>(qa, ka, va, pos, yh);
    k_proj_ln<<<256, 256, 0, stream>>>(wph, yh, x, b_proj, gamma, beta, (float*)d_out);
}

// Round 4
// 215.100 us; speedup vs baseline: 1.0926x; 1.0203x over previous
//
#include <hip/hip_runtime.h>
#include <hip/hip_bf16.h>
#include <math.h>

#define HW 4096
#define LN_EPS 1e-5f

typedef _Float16 half4v __attribute__((ext_vector_type(4)));
typedef _Float16 half8v __attribute__((ext_vector_type(8)));
typedef float float4v __attribute__((ext_vector_type(4)));

#if __has_builtin(__builtin_amdgcn_exp2f)
#define EXP2F(x) __builtin_amdgcn_exp2f(x)
#else
#define EXP2F(x) exp2f(x)
#endif

__device__ __forceinline__ half4v lo4(half8v v) { return __builtin_shufflevector(v, v, 0, 1, 2, 3); }
__device__ __forceinline__ half4v hi4(half8v v) { return __builtin_shufflevector(v, v, 4, 5, 6, 7); }

// perm32: stored position p holds index d = (p&3) + 4*((p>>3)&3) + 16*((p>>2)&1)
// so a b128 (8 halves) at p=quad*8 yields d = {quad*4+0..3, 16+quad*4+0..3} = the
// k-fragments of the two 16x16x16 MFMAs covering a 32-deep contraction.
__device__ __forceinline__ int inv32(int d) {
    return (d & 3) + (((d >> 4) & 1) << 2) + (((d >> 2) & 3) << 3);
}
// y swizzle: element (pos, o) stored at pos*256 + ((o>>3 ^ (pos&7))<<3) + (o&7)
__device__ __forceinline__ int yswz(int p, int o) {
    return ((((o >> 3) ^ (p & 7)) << 3) | (o & 7));
}

// ---------------- kernel 1: fp32 -> f16 conversions, vectorized 8/thread ----------------
__global__ void k_convert(const float* __restrict__ x, const float* __restrict__ wq,
                          const float* __restrict__ wp,
                          _Float16* __restrict__ xh, _Float16* __restrict__ wqh,
                          _Float16* __restrict__ wph) {
    const float qs = 0.17677669529663687f * 1.4426950408889634f; // scale * log2(e)
    int i = blockIdx.x * 256 + threadIdx.x;
    if (i < 262144) { // x: 512*4096/8 chunks
        float4v a = *(const float4v*)(x + i * 8);
        float4v b = *(const float4v*)(x + i * 8 + 4);
        half8v h;
        #pragma unroll
        for (int k = 0; k < 4; k++) { h[k] = (_Float16)a[k]; h[4 + k] = (_Float16)b[k]; }
        *(half8v*)(xh + i * 8) = h;
    }
    if (i < 49152) { // wq: 768*512/8 chunks; rows <256 (chunks <16384) pre-scaled
        float s = (i < 16384) ? qs : 1.0f;
        float4v a = *(const float4v*)(wq + i * 8);
        float4v b = *(const float4v*)(wq + i * 8 + 4);
        half8v h;
        #pragma unroll
        for (int k = 0; k < 4; k++) { h[k] = (_Float16)(a[k] * s); h[4 + k] = (_Float16)(b[k] * s); }
        *(half8v*)(wqh + i * 8) = h;
    }
    if (i < 16384) { // wp: 512*256/8 chunks
        float4v a = *(const float4v*)(wp + i * 8);
        float4v b = *(const float4v*)(wp + i * 8 + 4);
        half8v h;
        #pragma unroll
        for (int k = 0; k < 4; k++) { h[k] = (_Float16)a[k]; h[4 + k] = (_Float16)b[k]; }
        *(half8v*)(wph + i * 8) = h;
    }
}

// ---------------- kernel 2: pos bias bilinear 16 -> 64, times log2(e) ----------------
__global__ void k_pos(const float* __restrict__ pb, float* __restrict__ pos) {
    int i = blockIdx.x * 256 + threadIdx.x;
    if (i >= 8 * HW) return;
    int h = i >> 12, p = i & 4095, y = p >> 6, x = p & 63;
    float sy = y * 0.25f - 0.375f, sx = x * 0.25f - 0.375f;
    float fy = floorf(sy), fx = floorf(sx);
    float wy = sy - fy, wx = sx - fx;
    int y0 = (int)fy, x0 = (int)fx;
    int y1 = y0 + 1 < 15 ? y0 + 1 : 15;
    int x1 = x0 + 1 < 15 ? x0 + 1 : 15;
    y0 = y0 > 0 ? y0 : 0;
    x0 = x0 > 0 ? x0 : 0;
    const float* src = pb + h * 256;
    float v = (1.f - wy) * ((1.f - wx) * src[y0 * 16 + x0] + wx * src[y0 * 16 + x1]) +
              wy * ((1.f - wx) * src[y1 * 16 + x0] + wx * src[y1 * 16 + x1]);
    pos[i] = v * 1.4426950408889634f;
}

// ---------------- kernel 3: QKV GEMM (A = x^T staged in LDS, B = w from global) ----------
// Outputs permuted f16 layouts:
//   qa/ka: [h][pos][dperm32]  (Q pre-scaled by scale*log2e via wqh)
//   va:    [h*32+d][posperm32]
__global__ __launch_bounds__(256) void k_qkv(const _Float16* __restrict__ wqh,
                                             const _Float16* __restrict__ xh,
                                             _Float16* __restrict__ qa,
                                             _Float16* __restrict__ ka,
                                             _Float16* __restrict__ va) {
    __shared__ __attribute__((aligned(16))) _Float16 xs[64][72]; // [pos][c], padded
    int n0 = (blockIdx.x >> 6) * 64;  // out-channel tile base
    int p0 = (blockIdx.x & 63) * 64;  // position tile base
    int t = threadIdx.x, w = t >> 6, lane = t & 63, quad = lane >> 4, l16 = lane & 15;
    int sp = t & 63, scb = (t >> 6) * 16;

    float4v acc[4] = {};
    for (int k0 = 0; k0 < 512; k0 += 64) {
        __syncthreads();
        half8v v0, v1;
        #pragma unroll
        for (int cc = 0; cc < 8; cc++) v0[cc] = xh[(k0 + scb + cc) * HW + p0 + sp];
        #pragma unroll
        for (int cc = 0; cc < 8; cc++) v1[cc] = xh[(k0 + scb + 8 + cc) * HW + p0 + sp];
        *(half8v*)&xs[sp][scb] = v0;
        *(half8v*)&xs[sp][scb + 8] = v1;
        __syncthreads();
        #pragma unroll
        for (int kc = 0; kc < 2; kc++) {
            half8v a = *(const half8v*)&xs[w * 16 + l16][kc * 32 + quad * 8];
            #pragma unroll
            for (int nt = 0; nt < 4; nt++) {
                half8v b = *(const half8v*)&wqh[(n0 + nt * 16 + l16) * 512 + k0 + kc * 32 + quad * 8];
                acc[nt] = __builtin_amdgcn_mfma_f32_16x16x32_f16(a, b, acc[nt], 0, 0, 0);
            }
        }
    }
    // D: row=quad*4+r -> pos (this wave's 16-subtile), col=l16 -> out-channel
    #pragma unroll
    for (int nt = 0; nt < 4; nt++) {
        int o = n0 + nt * 16 + l16;
        #pragma unroll
        for (int r = 0; r < 4; r++) {
            int p = p0 + w * 16 + quad * 4 + r;
            _Float16 v = (_Float16)acc[nt][r];
            if (o < 256) {
                qa[(o >> 5) * 131072 + p * 32 + inv32(o & 31)] = v;
            } else if (o < 512) {
                ka[((o - 256) >> 5) * 131072 + p * 32 + inv32(o & 31)] = v;
            } else {
                va[(o - 512) * HW + (p & ~31) + inv32(p & 31)] = v;
            }
        }
    }
}

// ---------------- kernel 4: flash attention, j-split x4 within block ----------
// Block = 16 queries, 4 waves; wave w covers j in [w*1024, w*1024+1024).
// S^T = K.Q^T via 16x16x16 MFMA: C-layout of S^T == A-layout of P for PV.
__global__ __launch_bounds__(256, 6) void k_attn(const _Float16* __restrict__ qa,
                                                 const _Float16* __restrict__ ka,
                                                 const _Float16* __restrict__ va,
                                                 const float* __restrict__ pos,
                                                 _Float16* __restrict__ yh) {
    __shared__ float po[4][16][33]; // [wave][query][d], padded
    __shared__ float pl[4][16];
    int h = blockIdx.x >> 8;
    int q0 = (blockIdx.x & 255) * 16;
    int t = threadIdx.x, w = t >> 6, lane = t & 63, quad = lane >> 4, l16 = lane & 15;
    int jb = w * 1024;

    half8v qf = *(const half8v*)(qa + h * 131072 + (q0 + l16) * 32 + quad * 8);
    half4v qlo = lo4(qf), qhi = hi4(qf);
    const _Float16* kptr = ka + h * 131072 + l16 * 32 + quad * 8;
    const _Float16* vptr0 = va + h * 131072 + l16 * HW + quad * 8;
    const _Float16* vptr1 = vptr0 + 16 * HW;
    const float* pp = pos + h * HW + quad * 4;

    float4v o0 = {}, o1 = {};
    float lsum = 0.f;
    const float4v zero = {0.f, 0.f, 0.f, 0.f};

    for (int j0 = jb; j0 < jb + 1024; j0 += 32) {
        half8v kf0 = *(const half8v*)(kptr + j0 * 32);        // rows j0+l16
        half8v kf1 = *(const half8v*)(kptr + j0 * 32 + 512);  // rows j0+16+l16
        half8v vf0 = *(const half8v*)(vptr0 + j0);            // d = l16
        half8v vf1 = *(const half8v*)(vptr1 + j0);            // d = 16+l16
        float4v pb0 = *(const float4v*)(pp + j0);
        float4v pb1 = *(const float4v*)(pp + j0 + 16);

        // S^T sub-tiles: rows j, col query. Already includes scale*log2e (in Q).
        float4v s0 = __builtin_amdgcn_mfma_f32_16x16x16f16(lo4(kf0), qlo, zero, 0, 0, 0);
        s0 = __builtin_amdgcn_mfma_f32_16x16x16f16(hi4(kf0), qhi, s0, 0, 0, 0);
        float4v s1 = __builtin_amdgcn_mfma_f32_16x16x16f16(lo4(kf1), qlo, zero, 0, 0, 0);
        s1 = __builtin_amdgcn_mfma_f32_16x16x16f16(hi4(kf1), qhi, s1, 0, 0, 0);

        float e0 = EXP2F(s0[0] + pb0[0]);
        float e1 = EXP2F(s0[1] + pb0[1]);
        float e2 = EXP2F(s0[2] + pb0[2]);
        float e3 = EXP2F(s0[3] + pb0[3]);
        float e4 = EXP2F(s1[0] + pb1[0]);
        float e5 = EXP2F(s1[1] + pb1[1]);
        float e6 = EXP2F(s1[2] + pb1[2]);
        float e7 = EXP2F(s1[3] + pb1[3]);
        lsum += ((e0 + e1) + (e2 + e3)) + ((e4 + e5) + (e6 + e7));

        half4v pa0, pa1;
        pa0[0] = (_Float16)e0; pa0[1] = (_Float16)e1;
        pa0[2] = (_Float16)e2; pa0[3] = (_Float16)e3;
        pa1[0] = (_Float16)e4; pa1[1] = (_Float16)e5;
        pa1[2] = (_Float16)e6; pa1[3] = (_Float16)e7;

        o0 = __builtin_amdgcn_mfma_f32_16x16x16f16(pa0, lo4(vf0), o0, 0, 0, 0);
        o0 = __builtin_amdgcn_mfma_f32_16x16x16f16(pa1, hi4(vf0), o0, 0, 0, 0);
        o1 = __builtin_amdgcn_mfma_f32_16x16x16f16(pa0, lo4(vf1), o1, 0, 0, 0);
        o1 = __builtin_amdgcn_mfma_f32_16x16x16f16(pa1, hi4(vf1), o1, 0, 0, 0);
    }
    // per-wave l reduction: lane's partial is for query=l16; combine quads.
    lsum += __shfl_xor(lsum, 16, 64);
    lsum += __shfl_xor(lsum, 32, 64);
    // stash partials (O D-layout: row=quad*4+r -> query, col=l16 -> d)
    #pragma unroll
    for (int r = 0; r < 4; r++) {
        po[w][quad * 4 + r][l16] = o0[r];
        po[w][quad * 4 + r][16 + l16] = o1[r];
    }
    if (quad == 0) pl[w][l16] = lsum;
    __syncthreads();
    // combine 4 j-quarters: thread t -> (q = t>>4, d = t&15 and d+16)
    int q = t >> 4, d = t & 15;
    float v0 = (po[0][q][d] + po[1][q][d]) + (po[2][q][d] + po[3][q][d]);
    float v1 = (po[0][q][16 + d] + po[1][q][16 + d]) + (po[2][q][16 + d] + po[3][q][16 + d]);
    float l = (pl[0][q] + pl[1][q]) + (pl[2][q] + pl[3][q]);
    float inv = 1.f / l;
    int p = q0 + q;
    yh[p * 256 + yswz(p, h * 32 + d)] = (_Float16)(v0 * inv);
    yh[p * 256 + yswz(p, h * 32 + 16 + d)] = (_Float16)(v1 * inv);
}

// ---------------- kernel 5: proj GEMM + bias + residual + LayerNorm (16 waves) ----------
__global__ __launch_bounds__(1024) void k_proj_ln(const _Float16* __restrict__ wph,
                                                  const _Float16* __restrict__ yh,
                                                  const float* __restrict__ x,
                                                  const float* __restrict__ b_proj,
                                                  const float* __restrict__ gamma,
                                                  const float* __restrict__ beta,
                                                  float* __restrict__ out) {
    __shared__ __attribute__((aligned(16))) _Float16 ys[16 * 256]; // mirrors swizzled global
    __shared__ float red[2][16][17];
    int p0 = blockIdx.x * 16;
    int t = threadIdx.x, w = t >> 6, lane = t & 63, quad = lane >> 4, l16 = lane & 15;
    if (t < 512) *(half8v*)&ys[t * 8] = *(const half8v*)&yh[p0 * 256 + t * 8];
    __syncthreads();
    float4v acc[2] = {};
    #pragma unroll
    for (int kc = 0; kc < 8; kc++) {
        int u = (kc * 4 + quad) ^ (l16 & 7);
        half8v b = *(const half8v*)&ys[l16 * 256 + u * 8];
        #pragma unroll
        for (int mt = 0; mt < 2; mt++) {
            half8v a = *(const half8v*)&wph[(w * 32 + mt * 16 + l16) * 256 + kc * 32 + quad * 8];
            acc[mt] = __builtin_amdgcn_mfma_f32_16x16x32_f16(a, b, acc[mt], 0, 0, 0);
        }
    }
    int p = p0 + l16;
    float sum = 0.f, sumsq = 0.f;
    #pragma unroll
    for (int mt = 0; mt < 2; mt++)
        #pragma unroll
        for (int r = 0; r < 4; r++) {
            int c = w * 32 + mt * 16 + quad * 4 + r;
            float v = acc[mt][r] + b_proj[c] + x[c * HW + p];
            acc[mt][r] = v;
            sum += v;
            sumsq += v * v;
        }
    sum += __shfl_xor(sum, 16, 64);
    sum += __shfl_xor(sum, 32, 64);
    sumsq += __shfl_xor(sumsq, 16, 64);
    sumsq += __shfl_xor(sumsq, 32, 64);
    if (quad == 0) { red[0][w][l16] = sum; red[1][w][l16] = sumsq; }
    __syncthreads();
    float s0 = 0.f, s1 = 0.f;
    #pragma unroll
    for (int ww = 0; ww < 16; ww++) { s0 += red[0][ww][l16]; s1 += red[1][ww][l16]; }
    float mean = s0 * (1.f / 512.f);
    float var = s1 * (1.f / 512.f) - mean * mean;
    float rstd = rsqrtf(var + LN_EPS);
    #pragma unroll
    for (int mt = 0; mt < 2; mt++)
        #pragma unroll
        for (int r = 0; r < 4; r++) {
            int c = w * 32 + mt * 16 + quad * 4 + r;
            out[c * HW + p] = (acc[mt][r] - mean) * rstd * gamma[c] + beta[c];
        }
}

extern "C" void kernel_launch(void* const* d_in, const int* in_sizes, int n_in,
                              void* d_out, int out_size, void* d_ws, size_t ws_size,
                              hipStream_t stream) {
    const float* x      = (const float*)d_in[0];
    const float* w_qkv  = (const float*)d_in[1];
    const float* w_proj = (const float*)d_in[2];
    const float* b_proj = (const float*)d_in[3];
    const float* pos_b  = (const float*)d_in[4];
    const float* gamma  = (const float*)d_in[5];
    const float* beta   = (const float*)d_in[6];
    char* ws = (char*)d_ws;
    _Float16* xh  = (_Float16*)(ws);              // 512*4096*2   = 4194304
    _Float16* qa  = (_Float16*)(ws + 4194304);    // 8*4096*32*2  = 2097152
    _Float16* ka  = (_Float16*)(ws + 6291456);    // 2097152
    _Float16* va  = (_Float16*)(ws + 8388608);    // 2097152
    _Float16* yh  = (_Float16*)(ws + 10485760);   // 4096*256*2   = 2097152
    float*    pos = (float*)   (ws + 12582912);   // 8*4096*4     = 131072
    _Float16* wqh = (_Float16*)(ws + 12714240);   // 768*512*2    = 786432
    _Float16* wph = (_Float16*)(ws + 13500672);   // 512*256*2    = 262144

    k_convert<<<1024, 256, 0, stream>>>(x, w_qkv, w_proj, xh, wqh, wph);
    k_pos<<<128, 256, 0, stream>>>(pos_b, pos);
    k_qkv<<<768, 256, 0, stream>>>(wqh, xh, qa, ka, va);
    k_attn<<<2048, 256, 0, stream>>>(qa, ka, va, pos, yh);
    k_proj_ln<<<256, 1024, 0, stream>>>(wph, yh, x, b_proj, gamma, beta, (float*)d_out);
}